// Round 13
// baseline (234.569 us; speedup 1.0000x reference)
//
#include <hip/hip_runtime.h>

// Chamfer distance, B=16, N=M=4096, D=3.
// dist(i,j) = n1 + n2 - 2*x1.x2 as ONE bf16 MFMA per 32x32 tile (norms folded
// into padded K slots, hi/lo bf16 split => exact-grade; absmax 0.0 since R1).
// R17: DIAGNOSTIC round #2 (production = R16, 81.2 us, untouched).
// Main runs ~30 us vs 6.8 us MFMA floor; three x4-repeat probes discriminate:
//   A probe_mfma: folds removed, accs consumed via MFMA C-input chaining
//     (zero VALU) -> pure matrix+LDS pipeline time.
//   B probe_ref: production body x4 (reference).
//   C probe_pipe: deferred-fold pipeline (issue g, fold g-1; 8 live f32x16,
//     static names, even trip counts).
// Matrix: A~30 & C<<B -> adopt C. A~30 & C~B -> fold encoding (accvgpr).
//         A~B -> LDS/issue path or floor. Probes idempotent (rowpart dead;
//         guarded stores keep values live, rule 17).

typedef __attribute__((ext_vector_type(8))) __bf16 bf16x8;
typedef __attribute__((ext_vector_type(16))) float f32x16;

#define PTS 4096
#define NB 16

__device__ __forceinline__ unsigned f2bf(float f) {
  unsigned u = __float_as_uint(f);
  return (u + 0x7FFFu + ((u >> 16) & 1u)) >> 16;  // RNE bf16 bits
}
__device__ __forceinline__ float bf2f(unsigned s) {
  return __uint_as_float(s << 16);
}
__device__ __forceinline__ unsigned pk(unsigned lo, unsigned hi) {
  return (lo & 0xFFFFu) | (hi << 16);
}

// ---- shared prologue: build LDS B-panel + this thread's A fragments ----
__device__ __forceinline__ void build_panel_af(
    const float* __restrict__ x1, const float* __restrict__ x2,
    uint4* lds, bf16x8& af0, bf16x8& af1) {
  const int s  = blockIdx.x;
  const int d  = s & 1;
  const int b  = (s >> 1) & (NB - 1);
  const int ch = (s >> 5) & 1;
  const int rg = blockIdx.y;
  const int tid  = threadIdx.x;
  const int lane = tid & 63;
  const int half = lane >> 5;
  const int l31  = lane & 31;
  const int wave = tid >> 6;

  const float* Q = d ? x1 : x2;
  const int cbase = b * PTS + ch * 2048;
#pragma unroll
  for (int k = 0; k < 4; ++k) {
    const int j = tid + k * 512;
    const float* q = Q + (size_t)(cbase + j) * 3;
    const float x = q[0], y = q[1], z = q[2];
    const float sx = -2.f * x, sy = -2.f * y, sz = -2.f * z;
    const unsigned Hx = f2bf(sx), Hy = f2bf(sy), Hz = f2bf(sz);
    const unsigned Lx = f2bf(sx - bf2f(Hx));
    const unsigned Ly = f2bf(sy - bf2f(Hy));
    const unsigned Lz = f2bf(sz - bf2f(Hz));
    const float n = fmaf(x, x, fmaf(y, y, z * z));
    const unsigned nh = f2bf(n), nl = f2bf(n - bf2f(nh));
    const unsigned one = 0x3F80u;
    uint4 w0, w1;
    w0.x = pk(Hx, Hy); w0.y = pk(Hz, Lx); w0.z = pk(Ly, Lz); w0.w = pk(Hx, Hy);
    w1.x = pk(Hz, nh); w1.y = pk(nl, one); w1.z = pk(one, 0u); w1.w = 0u;
    lds[(j >> 5) * 64 + (j & 31)]      = w0;
    lds[(j >> 5) * 64 + 32 + (j & 31)] = w1;
  }

  const float* P = d ? x2 : x1;
  const int t0 = rg * 16 + wave * 2;
  bf16x8 af[2];
#pragma unroll
  for (int rr = 0; rr < 2; ++rr) {
    const int r = (t0 + rr) * 32 + l31;
    const float* p = P + (size_t)(b * PTS + r) * 3;
    const float x = p[0], y = p[1], zc = p[2];
    const unsigned hx = f2bf(x), hy = f2bf(y), hz = f2bf(zc);
    const unsigned lx = f2bf(x - bf2f(hx));
    const unsigned ly = f2bf(y - bf2f(hy));
    const unsigned lz = f2bf(zc - bf2f(hz));
    const float n = fmaf(x, x, fmaf(y, y, zc * zc));
    const unsigned nh = f2bf(n), nl = f2bf(n - bf2f(nh));
    const unsigned one = 0x3F80u;
    uint4 w0, w1;
    w0.x = pk(hx, hy); w0.y = pk(hz, hx); w0.z = pk(hy, hz); w0.w = pk(lx, ly);
    w1.x = pk(lz, one); w1.y = pk(one, nh); w1.z = pk(nl, 0u); w1.w = 0u;
    uint4 w;
    w.x = half ? w1.x : w0.x; w.y = half ? w1.y : w0.y;
    w.z = half ? w1.z : w0.z; w.w = half ? w1.w : w0.w;
    af[rr] = *(const bf16x8*)&w;
  }
  af0 = af[0];
  af1 = af[1];
}

// ---- production main (R16 verbatim semantics) ----
__global__ __launch_bounds__(512, 2) void chamfer_main(
    const float* __restrict__ x1, const float* __restrict__ x2,
    float* __restrict__ rowpart) {
  const int s  = blockIdx.x;
  const int d  = s & 1;
  const int b  = (s >> 1) & (NB - 1);
  const int ch = (s >> 5) & 1;
  const int rg = blockIdx.y;
  const int tid  = threadIdx.x;
  const int lane = tid & 63;
  const int half = lane >> 5;
  const int l31  = lane & 31;
  const int wave = tid >> 6;

  __shared__ uint4 lds[4096];
  bf16x8 af0, af1;
  build_panel_af(x1, x2, lds, af0, af1);

  f32x16 zero;
#pragma unroll
  for (int e = 0; e < 16; ++e) zero[e] = 0.f;
  float rm0[16], rm1[16];
#pragma unroll
  for (int e = 0; e < 16; ++e) { rm0[e] = 3.0e38f; rm1[e] = 3.0e38f; }

  __syncthreads();

  const uint4* tp = &lds[half * 32 + l31];
  bf16x8 buf[4];
  buf[0] = *(const bf16x8*)&tp[0];
  buf[1] = *(const bf16x8*)&tp[64];

#pragma unroll 2
  for (int g = 0; g < 32; ++g) {
    const int cur = (g & 1) * 2;
    const int nxt = ((g + 1) & 1) * 2;
    const int pf  = ((g + 1) & 31) * 2;
    buf[nxt]     = *(const bf16x8*)&tp[pf * 64];
    buf[nxt + 1] = *(const bf16x8*)&tp[(pf + 1) * 64];
    const bf16x8 b0 = buf[cur], b1 = buf[cur + 1];
    const f32x16 a00 =
        __builtin_amdgcn_mfma_f32_32x32x16_bf16(af0, b0, zero, 0, 0, 0);
    const f32x16 a01 =
        __builtin_amdgcn_mfma_f32_32x32x16_bf16(af0, b1, zero, 0, 0, 0);
#pragma unroll
    for (int e = 0; e < 16; ++e)
      rm0[e] = fminf(fminf(a00[e], a01[e]), rm0[e]);
    const f32x16 a10 =
        __builtin_amdgcn_mfma_f32_32x32x16_bf16(af1, b0, zero, 0, 0, 0);
    const f32x16 a11 =
        __builtin_amdgcn_mfma_f32_32x32x16_bf16(af1, b1, zero, 0, 0, 0);
#pragma unroll
    for (int e = 0; e < 16; ++e)
      rm1[e] = fminf(fminf(a10[e], a11[e]), rm1[e]);
  }

  const int t0 = rg * 16 + wave * 2;
  float* rbase = rowpart + ((size_t)((ch * 2 + d) * NB + b)) * PTS + t0 * 32;
#pragma unroll
  for (int e = 0; e < 16; ++e) {
    float v = rm0[e];
    v = fminf(v, __shfl_xor(v, 1));
    v = fminf(v, __shfl_xor(v, 2));
    v = fminf(v, __shfl_xor(v, 4));
    v = fminf(v, __shfl_xor(v, 8));
    v = fminf(v, __shfl_xor(v, 16));
    if (l31 == e) rbase[(e & 3) + 8 * (e >> 2) + 4 * half] = fmaxf(v, 0.f);
  }
#pragma unroll
  for (int e = 0; e < 16; ++e) {
    float v = rm1[e];
    v = fminf(v, __shfl_xor(v, 1));
    v = fminf(v, __shfl_xor(v, 2));
    v = fminf(v, __shfl_xor(v, 4));
    v = fminf(v, __shfl_xor(v, 8));
    v = fminf(v, __shfl_xor(v, 16));
    if (l31 == e) rbase[32 + (e & 3) + 8 * (e >> 2) + 4 * half] = fmaxf(v, 0.f);
  }
}

// ---- probe A: pure MFMA+LDS pipeline (accs chained via C-input, no VALU) ----
__global__ __launch_bounds__(512, 2) void probe_mfma(
    const float* __restrict__ x1, const float* __restrict__ x2,
    float* __restrict__ sink) {
  __shared__ uint4 lds[4096];
  bf16x8 af0, af1;
  build_panel_af(x1, x2, lds, af0, af1);
  f32x16 c0, c1, c2, c3;
#pragma unroll
  for (int e = 0; e < 16; ++e) { c0[e] = 0.f; c1[e] = 0.f; c2[e] = 0.f; c3[e] = 0.f; }
  __syncthreads();
  const int lane = threadIdx.x & 63;
  const uint4* tp = &lds[(lane >> 5) * 32 + (lane & 31)];
  for (int rep = 0; rep < 4; ++rep) {
    bf16x8 buf[4];
    buf[0] = *(const bf16x8*)&tp[0];
    buf[1] = *(const bf16x8*)&tp[64];
#pragma unroll 2
    for (int g = 0; g < 32; ++g) {
      const int cur = (g & 1) * 2;
      const int nxt = ((g + 1) & 1) * 2;
      const int pf  = ((g + 1) & 31) * 2;
      buf[nxt]     = *(const bf16x8*)&tp[pf * 64];
      buf[nxt + 1] = *(const bf16x8*)&tp[(pf + 1) * 64];
      const bf16x8 b0 = buf[cur], b1 = buf[cur + 1];
      c0 = __builtin_amdgcn_mfma_f32_32x32x16_bf16(af0, b0, c0, 0, 0, 0);
      c1 = __builtin_amdgcn_mfma_f32_32x32x16_bf16(af0, b1, c1, 0, 0, 0);
      c2 = __builtin_amdgcn_mfma_f32_32x32x16_bf16(af1, b0, c2, 0, 0, 0);
      c3 = __builtin_amdgcn_mfma_f32_32x32x16_bf16(af1, b1, c3, 0, 0, 0);
    }
  }
  if (__float_as_uint(x1[0]) == 0x7F123456u) {  // never true in practice
    float t = 0.f;
#pragma unroll
    for (int e = 0; e < 16; ++e) t += c0[e] + c1[e] + c2[e] + c3[e];
    sink[threadIdx.x] = t;
  }
}

// ---- probe B: production body x4 (guarded store) ----
__global__ __launch_bounds__(512, 2) void probe_ref(
    const float* __restrict__ x1, const float* __restrict__ x2,
    float* __restrict__ sink) {
  __shared__ uint4 lds[4096];
  bf16x8 af0, af1;
  build_panel_af(x1, x2, lds, af0, af1);
  f32x16 zero;
#pragma unroll
  for (int e = 0; e < 16; ++e) zero[e] = 0.f;
  float rm0[16], rm1[16];
#pragma unroll
  for (int e = 0; e < 16; ++e) { rm0[e] = 3.0e38f; rm1[e] = 3.0e38f; }
  __syncthreads();
  const int lane = threadIdx.x & 63;
  const uint4* tp = &lds[(lane >> 5) * 32 + (lane & 31)];
  for (int rep = 0; rep < 4; ++rep) {
    bf16x8 buf[4];
    buf[0] = *(const bf16x8*)&tp[0];
    buf[1] = *(const bf16x8*)&tp[64];
#pragma unroll 2
    for (int g = 0; g < 32; ++g) {
      const int cur = (g & 1) * 2;
      const int nxt = ((g + 1) & 1) * 2;
      const int pf  = ((g + 1) & 31) * 2;
      buf[nxt]     = *(const bf16x8*)&tp[pf * 64];
      buf[nxt + 1] = *(const bf16x8*)&tp[(pf + 1) * 64];
      const bf16x8 b0 = buf[cur], b1 = buf[cur + 1];
      const f32x16 a00 =
          __builtin_amdgcn_mfma_f32_32x32x16_bf16(af0, b0, zero, 0, 0, 0);
      const f32x16 a01 =
          __builtin_amdgcn_mfma_f32_32x32x16_bf16(af0, b1, zero, 0, 0, 0);
#pragma unroll
      for (int e = 0; e < 16; ++e)
        rm0[e] = fminf(fminf(a00[e], a01[e]), rm0[e]);
      const f32x16 a10 =
          __builtin_amdgcn_mfma_f32_32x32x16_bf16(af1, b0, zero, 0, 0, 0);
      const f32x16 a11 =
          __builtin_amdgcn_mfma_f32_32x32x16_bf16(af1, b1, zero, 0, 0, 0);
#pragma unroll
      for (int e = 0; e < 16; ++e)
        rm1[e] = fminf(fminf(a10[e], a11[e]), rm1[e]);
    }
  }
  if (__float_as_uint(x1[0]) == 0x7F123456u) {
    float t = 0.f;
#pragma unroll
    for (int e = 0; e < 16; ++e) t += rm0[e] + rm1[e];
    sink[threadIdx.x] = t;
  }
}

// ---- probe C: deferred-fold pipeline (issue g, fold g-1; 8 live f32x16) ----
#define ISSUE4(P0, P1, P2, P3, CUR)                                           \
  do {                                                                        \
    const bf16x8 b0v = buf[CUR], b1v = buf[(CUR) + 1];                        \
    P0 = __builtin_amdgcn_mfma_f32_32x32x16_bf16(af0, b0v, zero, 0, 0, 0);    \
    P1 = __builtin_amdgcn_mfma_f32_32x32x16_bf16(af0, b1v, zero, 0, 0, 0);    \
    P2 = __builtin_amdgcn_mfma_f32_32x32x16_bf16(af1, b0v, zero, 0, 0, 0);    \
    P3 = __builtin_amdgcn_mfma_f32_32x32x16_bf16(af1, b1v, zero, 0, 0, 0);    \
  } while (0)
#define FOLD4(P0, P1, P2, P3)                                                 \
  do {                                                                        \
    _Pragma("unroll") for (int e = 0; e < 16; ++e)                            \
        rm0[e] = fminf(fminf(P0[e], P1[e]), rm0[e]);                          \
    _Pragma("unroll") for (int e = 0; e < 16; ++e)                            \
        rm1[e] = fminf(fminf(P2[e], P3[e]), rm1[e]);                          \
  } while (0)

__global__ __launch_bounds__(512, 2) void probe_pipe(
    const float* __restrict__ x1, const float* __restrict__ x2,
    float* __restrict__ sink) {
  __shared__ uint4 lds[4096];
  bf16x8 af0, af1;
  build_panel_af(x1, x2, lds, af0, af1);
  f32x16 zero;
#pragma unroll
  for (int e = 0; e < 16; ++e) zero[e] = 0.f;
  float rm0[16], rm1[16];
#pragma unroll
  for (int e = 0; e < 16; ++e) { rm0[e] = 3.0e38f; rm1[e] = 3.0e38f; }
  __syncthreads();
  const int lane = threadIdx.x & 63;
  const uint4* tp = &lds[(lane >> 5) * 32 + (lane & 31)];
  for (int rep = 0; rep < 4; ++rep) {
    bf16x8 buf[4];
    buf[0] = *(const bf16x8*)&tp[0];
    buf[1] = *(const bf16x8*)&tp[64];
    f32x16 pA0, pA1, pA2, pA3, pB0, pB1, pB2, pB3;
    // step 0 (A-set): prefetch tiles 2,3; issue from tiles 0,1
    buf[2] = *(const bf16x8*)&tp[2 * 64];
    buf[3] = *(const bf16x8*)&tp[3 * 64];
    ISSUE4(pA0, pA1, pA2, pA3, 0);
#pragma unroll 2
    for (int g = 1; g < 31; ++g) {  // 30 iterations (even): static indices
      const int cur = (g & 1) * 2;
      const int nxt = ((g + 1) & 1) * 2;
      const int pf  = ((g + 1) & 31) * 2;
      buf[nxt]     = *(const bf16x8*)&tp[pf * 64];
      buf[nxt + 1] = *(const bf16x8*)&tp[(pf + 1) * 64];
      if (g & 1) {
        ISSUE4(pB0, pB1, pB2, pB3, 2);
        FOLD4(pA0, pA1, pA2, pA3);
      } else {
        ISSUE4(pA0, pA1, pA2, pA3, 0);
        FOLD4(pB0, pB1, pB2, pB3);
      }
    }
    // step 31 (odd -> B-set from buf[2..3]); then drain both
    ISSUE4(pB0, pB1, pB2, pB3, 2);
    FOLD4(pA0, pA1, pA2, pA3);
    FOLD4(pB0, pB1, pB2, pB3);
  }
  if (__float_as_uint(x1[0]) == 0x7F123456u) {
    float t = 0.f;
#pragma unroll
    for (int e = 0; e < 16; ++e) t += rm0[e] + rm1[e];
    sink[threadIdx.x] = t;
  }
}

// ---- reduce: out[b] = mean_r min(ch0,ch1)[d=0] + mean_r min(ch0,ch1)[d=1] ----
__global__ __launch_bounds__(512) void reduce_rows(
    const float* __restrict__ rowpart, float* __restrict__ out) {
  const int b = blockIdx.x;
  const int tid = threadIdx.x;
  const float* p0 = rowpart + (size_t)(0 * NB + b) * PTS;
  const float* p1 = rowpart + (size_t)(1 * NB + b) * PTS;
  const float* p2 = rowpart + (size_t)(2 * NB + b) * PTS;
  const float* p3 = rowpart + (size_t)(3 * NB + b) * PTS;
  float s = 0.f;
  for (int i = tid; i < PTS; i += 512)
    s += fminf(p0[i], p2[i]) + fminf(p1[i], p3[i]);
  s += __shfl_xor(s, 1);
  s += __shfl_xor(s, 2);
  s += __shfl_xor(s, 4);
  s += __shfl_xor(s, 8);
  s += __shfl_xor(s, 16);
  s += __shfl_xor(s, 32);
  __shared__ float acc[8];
  if ((tid & 63) == 0) acc[tid >> 6] = s;
  __syncthreads();
  if (tid == 0) {
    float t = 0.f;
#pragma unroll
    for (int w = 0; w < 8; ++w) t += acc[w];
    out[b] = t * (1.f / PTS);
  }
}

extern "C" void kernel_launch(void* const* d_in, const int* in_sizes, int n_in,
                              void* d_out, int out_size, void* d_ws,
                              size_t ws_size, hipStream_t stream) {
  const float* x1 = (const float*)d_in[0];
  const float* x2 = (const float*)d_in[1];
  float* out = (float*)d_out;

  float* rowpart = (float*)d_ws;  // 4*NB*PTS floats = 1 MB, fully overwritten

  dim3 grid(64, 8);
  chamfer_main<<<grid, 512, 0, stream>>>(x1, x2, rowpart);
  reduce_rows<<<NB, 512, 0, stream>>>(rowpart, out);
  // Diagnostics (idempotent; rowpart dead after reduce_rows).
  probe_mfma<<<grid, 512, 0, stream>>>(x1, x2, rowpart);
  probe_ref<<<grid, 512, 0, stream>>>(x1, x2, rowpart);
  probe_pipe<<<grid, 512, 0, stream>>>(x1, x2, rowpart);
}

// Round 15
// 81.188 us; speedup vs baseline: 2.8892x; 2.8892x over previous
//
#include <hip/hip_runtime.h>

// Chamfer distance, B=16, N=M=4096, D=3.
// dist(i,j) = n1 + n2 - 2*x1.x2 as ONE bf16 MFMA per 32x32 tile (norms folded
// into padded K slots, hi/lo bf16 split => exact-grade; absmax 0.0 since R1).
// R19: revert R18's cooperative fusion (absmax 0.074: cross-XCD L2 staleness
// on plain stores, G16 — the pre-committed failure mode). Production = R16
// (81.2 us best, two dispatches) + ONE safe change: per-wave s_sleep stagger
// (0..~900cyc across 8 waves) after the barrier. R17 counters showed
// MFMA-busy + VALU-busy ~= total (waves phase-locked, matrix pipe idle 52%);
// no in-loop barriers -> once staggered, waves stay staggered, one wave's
// MFMA phase overlaps another's fold phase.

typedef __attribute__((ext_vector_type(8))) __bf16 bf16x8;
typedef __attribute__((ext_vector_type(16))) float f32x16;

#define PTS 4096
#define NB 16

__device__ __forceinline__ unsigned f2bf(float f) {
  unsigned u = __float_as_uint(f);
  return (u + 0x7FFFu + ((u >> 16) & 1u)) >> 16;  // RNE bf16 bits
}
__device__ __forceinline__ float bf2f(unsigned s) {
  return __uint_as_float(s << 16);
}
__device__ __forceinline__ unsigned pk(unsigned lo, unsigned hi) {
  return (lo & 0xFFFFu) | (hi << 16);
}

// ---- main: 512 threads (8 waves). Block builds its 64-tile (2048-col)
// B-panel in LDS from raw points, then all 8 waves stream it (2 row-tiles
// per wave = 512 rows/block). grid.x = 64 slices (dir,b,ch) -> XCD = x%8 ;
// grid.y = 8 row-groups. 512 blocks = 2/CU (64KB LDS), 4 waves/SIMD (reg cap).
__global__ __launch_bounds__(512, 2) void chamfer_main(
    const float* __restrict__ x1, const float* __restrict__ x2,
    float* __restrict__ rowpart) {
  const int s  = blockIdx.x;           // 64 slices: (dir, batch, colhalf)
  const int d  = s & 1;
  const int b  = (s >> 1) & (NB - 1);
  const int ch = (s >> 5) & 1;
  const int rg = blockIdx.y;           // 8 row-groups of 512 rows

  const int tid  = threadIdx.x;
  const int lane = tid & 63;
  const int half = lane >> 5;          // K-half this lane supplies to MFMA
  const int l31  = lane & 31;
  const int wave = tid >> 6;           // 0..7

  __shared__ uint4 lds[4096];          // 64 tiles x 1 KB = 64 KB

  // --- build B-panel in LDS from raw col-side points ---
  // B k-vec: w0=[Hx Hy Hz Lx Ly Lz Hx Hy] w1=[Hz nh nl 1 1 0 0 0], H,L = -2q.
  const float* Q = d ? x1 : x2;        // col side = opposite of row side
  const int cbase = b * PTS + ch * 2048;
#pragma unroll
  for (int k = 0; k < 4; ++k) {
    const int j = tid + k * 512;       // 2048 panel points
    const float* q = Q + (size_t)(cbase + j) * 3;
    const float x = q[0], y = q[1], z = q[2];
    const float sx = -2.f * x, sy = -2.f * y, sz = -2.f * z;
    const unsigned Hx = f2bf(sx), Hy = f2bf(sy), Hz = f2bf(sz);
    const unsigned Lx = f2bf(sx - bf2f(Hx));
    const unsigned Ly = f2bf(sy - bf2f(Hy));
    const unsigned Lz = f2bf(sz - bf2f(Hz));
    const float n = fmaf(x, x, fmaf(y, y, z * z));
    const unsigned nh = f2bf(n), nl = f2bf(n - bf2f(nh));
    const unsigned one = 0x3F80u;
    uint4 w0, w1;
    w0.x = pk(Hx, Hy); w0.y = pk(Hz, Lx); w0.z = pk(Ly, Lz); w0.w = pk(Hx, Hy);
    w1.x = pk(Hz, nh); w1.y = pk(nl, one); w1.z = pk(one, 0u); w1.w = 0u;
    lds[(j >> 5) * 64 + (j & 31)]      = w0;  // half 0 (k 0..7)
    lds[(j >> 5) * 64 + 32 + (j & 31)] = w1;  // half 1 (k 8..15)
  }

  // --- build A fragments from raw points (row tiles t0, t0+1) ---
  // A k-vec: w0=[hx hy hz hx hy hz lx ly]  w1=[lz 1 1 nh nl 0 0 0]
  const float* P = d ? x2 : x1;
  const int t0 = rg * 16 + wave * 2;
  bf16x8 af[2];
#pragma unroll
  for (int rr = 0; rr < 2; ++rr) {
    const int r = (t0 + rr) * 32 + l31;
    const float* p = P + (size_t)(b * PTS + r) * 3;
    const float x = p[0], y = p[1], zc = p[2];
    const unsigned hx = f2bf(x), hy = f2bf(y), hz = f2bf(zc);
    const unsigned lx = f2bf(x - bf2f(hx));
    const unsigned ly = f2bf(y - bf2f(hy));
    const unsigned lz = f2bf(zc - bf2f(hz));
    const float n = fmaf(x, x, fmaf(y, y, zc * zc));
    const unsigned nh = f2bf(n), nl = f2bf(n - bf2f(nh));
    const unsigned one = 0x3F80u;
    uint4 w0, w1;
    w0.x = pk(hx, hy); w0.y = pk(hz, hx); w0.z = pk(hy, hz); w0.w = pk(lx, ly);
    w1.x = pk(lz, one); w1.y = pk(one, nh); w1.z = pk(nl, 0u); w1.w = 0u;
    uint4 w;
    w.x = half ? w1.x : w0.x; w.y = half ? w1.y : w0.y;
    w.z = half ? w1.z : w0.z; w.w = half ? w1.w : w0.w;
    af[rr] = *(const bf16x8*)&w;
  }
  const bf16x8 af0 = af[0], af1 = af[1];

  f32x16 zero;
#pragma unroll
  for (int e = 0; e < 16; ++e) zero[e] = 0.f;

  float rm0[16], rm1[16];
#pragma unroll
  for (int e = 0; e < 16; ++e) { rm0[e] = 3.0e38f; rm1[e] = 3.0e38f; }

  __syncthreads();  // panel staged (read-only afterwards: no more barriers)

  // --- phase-stagger: desync the 8 waves' MFMA/fold cycles (R17: lock-step
  // leaves matrix pipe idle 52%; no in-loop barriers keeps them staggered) ---
  for (int i = 0; i < wave; ++i) __builtin_amdgcn_s_sleep(2);

  // --- stream 64 tiles from LDS; 4-slot ring, 2 reads in flight ---
  const uint4* tp = &lds[half * 32 + l31];  // tile stride = 64 uint4
  bf16x8 buf[4];
  buf[0] = *(const bf16x8*)&tp[0];
  buf[1] = *(const bf16x8*)&tp[64];

#pragma unroll 2
  for (int g = 0; g < 32; ++g) {
    const int cur = (g & 1) * 2;
    const int nxt = ((g + 1) & 1) * 2;
    const int pf  = ((g + 1) & 31) * 2;  // wrap: last prefetch redundant, safe
    buf[nxt]     = *(const bf16x8*)&tp[pf * 64];
    buf[nxt + 1] = *(const bf16x8*)&tp[(pf + 1) * 64];
    const bf16x8 b0 = buf[cur], b1 = buf[cur + 1];
    const f32x16 a00 =
        __builtin_amdgcn_mfma_f32_32x32x16_bf16(af0, b0, zero, 0, 0, 0);
    const f32x16 a01 =
        __builtin_amdgcn_mfma_f32_32x32x16_bf16(af0, b1, zero, 0, 0, 0);
#pragma unroll
    for (int e = 0; e < 16; ++e)
      rm0[e] = fminf(fminf(a00[e], a01[e]), rm0[e]);  // v_min3_f32
    const f32x16 a10 =
        __builtin_amdgcn_mfma_f32_32x32x16_bf16(af1, b0, zero, 0, 0, 0);
    const f32x16 a11 =
        __builtin_amdgcn_mfma_f32_32x32x16_bf16(af1, b1, zero, 0, 0, 0);
#pragma unroll
    for (int e = 0; e < 16; ++e)
      rm1[e] = fminf(fminf(a10[e], a11[e]), rm1[e]);
  }

  // --- per-row min over this wave's 32 cols-per-half, direct store ---
  // C/D layout: col = lane&31, row_local = (e&3) + 8*(e>>2) + 4*half.
  // Each row written exactly once per col-half: no init, no atomics.
  float* rbase = rowpart + ((size_t)((ch * 2 + d) * NB + b)) * PTS + t0 * 32;
#pragma unroll
  for (int e = 0; e < 16; ++e) {
    float v = rm0[e];
    v = fminf(v, __shfl_xor(v, 1));
    v = fminf(v, __shfl_xor(v, 2));
    v = fminf(v, __shfl_xor(v, 4));
    v = fminf(v, __shfl_xor(v, 8));
    v = fminf(v, __shfl_xor(v, 16));
    if (l31 == e) {
      const int rl = (e & 3) + 8 * (e >> 2) + 4 * half;
      rbase[rl] = fmaxf(v, 0.f);
    }
  }
#pragma unroll
  for (int e = 0; e < 16; ++e) {
    float v = rm1[e];
    v = fminf(v, __shfl_xor(v, 1));
    v = fminf(v, __shfl_xor(v, 2));
    v = fminf(v, __shfl_xor(v, 4));
    v = fminf(v, __shfl_xor(v, 8));
    v = fminf(v, __shfl_xor(v, 16));
    if (l31 == e) {
      const int rl = 32 + (e & 3) + 8 * (e >> 2) + 4 * half;
      rbase[rl] = fmaxf(v, 0.f);
    }
  }
}

// ---- reduce: out[b] = mean_r min(ch0,ch1)[d=0] + mean_r min(ch0,ch1)[d=1] ----
// Planes: p = ch*2 + d -> d=0 in planes {0,2}, d=1 in planes {1,3}.
__global__ __launch_bounds__(512) void reduce_rows(
    const float* __restrict__ rowpart, float* __restrict__ out) {
  const int b = blockIdx.x;
  const int tid = threadIdx.x;
  const float* p0 = rowpart + (size_t)(0 * NB + b) * PTS;  // ch0,d0
  const float* p1 = rowpart + (size_t)(1 * NB + b) * PTS;  // ch0,d1
  const float* p2 = rowpart + (size_t)(2 * NB + b) * PTS;  // ch1,d0
  const float* p3 = rowpart + (size_t)(3 * NB + b) * PTS;  // ch1,d1
  float s = 0.f;
  for (int i = tid; i < PTS; i += 512)
    s += fminf(p0[i], p2[i]) + fminf(p1[i], p3[i]);
  s += __shfl_xor(s, 1);
  s += __shfl_xor(s, 2);
  s += __shfl_xor(s, 4);
  s += __shfl_xor(s, 8);
  s += __shfl_xor(s, 16);
  s += __shfl_xor(s, 32);
  __shared__ float acc[8];
  if ((tid & 63) == 0) acc[tid >> 6] = s;
  __syncthreads();
  if (tid == 0) {
    float t = 0.f;
#pragma unroll
    for (int w = 0; w < 8; ++w) t += acc[w];
    out[b] = t * (1.f / PTS);
  }
}

extern "C" void kernel_launch(void* const* d_in, const int* in_sizes, int n_in,
                              void* d_out, int out_size, void* d_ws,
                              size_t ws_size, hipStream_t stream) {
  const float* x1 = (const float*)d_in[0];
  const float* x2 = (const float*)d_in[1];
  float* out = (float*)d_out;

  float* rowpart = (float*)d_ws;  // 4*NB*PTS floats = 1 MB, fully overwritten

  dim3 grid(64, 8);  // x = (dir,b,ch) slice -> XCD = x%8 ; y = row-group
  chamfer_main<<<grid, 512, 0, stream>>>(x1, x2, rowpart);
  reduce_rows<<<NB, 512, 0, stream>>>(rowpart, out);
}